// Round 1
// 100.978 us; speedup vs baseline: 1.0107x; 1.0107x over previous
//
#include <hip/hip_runtime.h>

// Fully-fused FraudDetectionHybrid forward, round 3.
// R2 analysis: timed region = 2 harness poison-fills (~87 us, immovable, already
// at 77-79% HBM peak) + this kernel (~15 us, ~5x off its own ~3 us roofline).
// This round attacks the kernel's instruction/latency bound:
//  - raw v_exp_f32 via __builtin_amdgcn_exp2f (exp2f expands to ~5 instrs with
//    a denormal guard; 14 exps/sample made that ~1/3 of all VALU work)
//  - 2 samples/thread (one float4 in -> one float4 out): 524288 threads,
//    8 blocks/CU -> 32 waves/CU (was 16), perfect per-instruction coalescing
//  - softmax via logit-difference only: d = (l1-l0)*log2e computed with 4 fma
//    against prefolded (w2[1,:]-w2[0,:])*log2e; p0 = rcp(1+exp2(d))
//  - conv weights prefolded with -log2e
//  - nontemporal load/store (both buffers touched exactly once)
//
// Saturation safety unchanged: exp2(large)=inf -> rcp(inf)=0, so tanh/sigmoid/
// softmax clamp exactly to {-1,1}/{0,1} at extremes; no NaNs.

#define LOG2E 1.44269504088896f

typedef float v4f __attribute__((ext_vector_type(4)));

__device__ __forceinline__ float frcp(float x)  { return __builtin_amdgcn_rcpf(x); }
__device__ __forceinline__ float fexp2(float x) { return __builtin_amdgcn_exp2f(x); }

__device__ __forceinline__ float ftanh(float x) {
    // tanh(x) = 1 - 2/(exp2(2*log2e*x)+1)
    return 1.0f - 2.0f * frcp(fexp2(2.0f * LOG2E * x) + 1.0f);
}

__global__ __launch_bounds__(256) void fraud_fused_kernel(
    const v4f* __restrict__ x,         // [B/2] float4 = 2 samples each
    v4f* __restrict__ out,
    const float* __restrict__ fW,      // [4,2,2]
    const float* __restrict__ fb,      // [4,2]
    const float* __restrict__ ck,      // [2,2]
    const float* __restrict__ sW1,     // [4,2]
    const float* __restrict__ sb1,     // [4]
    const float* __restrict__ sW2,     // [2,4]
    const float* __restrict__ sb2,     // [2]
    int n)                             // B/2 float4s, one per thread
{
    int i = blockIdx.x * blockDim.x + threadIdx.x;
    if (i >= n) return;

    // Wave-uniform weight preloads -> scalar loads, L2-resident.
    float W[16];
    #pragma unroll
    for (int k = 0; k < 16; ++k) W[k] = fW[k];
    float bb[8];
    #pragma unroll
    for (int k = 0; k < 8; ++k) bb[k] = fb[k];
    // conv: sigmoid(sum(patch*ck)) with patch rows both = (h0,h1):
    // cs = h0*(ck0+ck2) + h1*(ck1+ck3); prefold -log2e for exp2.
    const float ckx = -LOG2E * (ck[0] + ck[2]);
    const float cky = -LOG2E * (ck[1] + ck[3]);
    float w1[8];
    #pragma unroll
    for (int k = 0; k < 8; ++k) w1[k] = sW1[k];
    float b1[4];
    #pragma unroll
    for (int k = 0; k < 4; ++k) b1[k] = sb1[k];
    // softmax needs only l1-l0: prefold log2e*(row1-row0).
    const float dw0 = LOG2E * (sW2[4] - sW2[0]);
    const float dw1 = LOG2E * (sW2[5] - sW2[1]);
    const float dw2 = LOG2E * (sW2[6] - sW2[2]);
    const float dw3 = LOG2E * (sW2[7] - sW2[3]);
    const float db  = LOG2E * (sb2[1] - sb2[0]);

    v4f xv = __builtin_nontemporal_load(x + i);
    float hx[2] = {xv.x, xv.z};
    float hy[2] = {xv.y, xv.w};
    float r[4];

    #pragma unroll
    for (int s = 0; s < 2; ++s) {
        float h0 = hx[s], h1 = hy[s];

        // fraud net: 4x tanh(2x2 affine)
        #pragma unroll
        for (int l = 0; l < 4; ++l) {
            float a0 = fmaf(h0, W[4*l + 0], fmaf(h1, W[4*l + 1], bb[2*l + 0]));
            float a1 = fmaf(h0, W[4*l + 2], fmaf(h1, W[4*l + 3], bb[2*l + 1]));
            h0 = ftanh(a0);
            h1 = ftanh(a1);
        }

        // conv surrogate + sigmoid (weights prefolded with -log2e)
        float conv = frcp(1.0f + fexp2(fmaf(h0, ckx, h1 * cky)));

        // sampler hidden layer
        float t0 = ftanh(fmaf(h0, w1[0], fmaf(conv, w1[1], b1[0])));
        float t1 = ftanh(fmaf(h0, w1[2], fmaf(conv, w1[3], b1[1])));
        float t2 = ftanh(fmaf(h0, w1[4], fmaf(conv, w1[5], b1[2])));
        float t3 = ftanh(fmaf(h0, w1[6], fmaf(conv, w1[7], b1[3])));

        // 2-way softmax from the logit difference only:
        // d = log2e*(l1-l0); p0 = 1/(1+2^d); p1 = 1-p0. exp->inf => p0=0 exact.
        float d  = fmaf(t0, dw0, fmaf(t1, dw1, fmaf(t2, dw2, fmaf(t3, dw3, db))));
        float p0 = frcp(1.0f + fexp2(d));
        r[2*s + 0] = p0;
        r[2*s + 1] = 1.0f - p0;
    }

    v4f o;
    o.x = r[0]; o.y = r[1]; o.z = r[2]; o.w = r[3];
    __builtin_nontemporal_store(o, out + i);
}

extern "C" void kernel_launch(void* const* d_in, const int* in_sizes, int n_in,
                              void* d_out, int out_size, void* d_ws, size_t ws_size,
                              hipStream_t stream) {
    // 0:x 1:fraud_W 2:fraud_b 3..14:enc/dec (dead) 15:conv_k 16:s_W1 17:s_b1 18:s_W2 19:s_b2
    const v4f* x     = (const v4f*)d_in[0];
    const float* fW  = (const float*)d_in[1];
    const float* fb  = (const float*)d_in[2];
    const float* ck  = (const float*)d_in[15];
    const float* sW1 = (const float*)d_in[16];
    const float* sb1 = (const float*)d_in[17];
    const float* sW2 = (const float*)d_in[18];
    const float* sb2 = (const float*)d_in[19];
    v4f* out = (v4f*)d_out;

    const int n = in_sizes[0] / 4;      // float4 count (in_sizes are element counts)
    const int block = 256;
    const int grid = (n + block - 1) / block;

    fraud_fused_kernel<<<grid, block, 0, stream>>>(
        x, out, fW, fb, ck, sW1, sb1, sW2, sb2, n);
}